// Round 1
// baseline (622.139 us; speedup 1.0000x reference)
//
#include <hip/hip_runtime.h>
#include <cstdint>
#include <cstddef>

#define M_TOT 8192
#define N_TOT 4096
#define K_TOT 4096
#define RANK  16
#define BM 128
#define BN 128
#define BK 32

typedef float f32x4 __attribute__((ext_vector_type(4)));
typedef __bf16 bf16x8 __attribute__((ext_vector_type(8)));
typedef unsigned short u16x4 __attribute__((ext_vector_type(4)));

__device__ __forceinline__ unsigned short f32_to_bf16(float f) {
    union { float f; uint32_t u; } v; v.f = f;
    uint32_t r = v.u + (0x7fffu + ((v.u >> 16) & 1u));
    return (unsigned short)(r >> 16);
}

// width-16 async global->LDS. dst is wave-uniform base; HW writes lane i at base + i*16B.
__device__ __forceinline__ void gload_lds16(const void* g, void* l) {
    __builtin_amdgcn_global_load_lds(
        (const __attribute__((address_space(1))) void*)g,
        (__attribute__((address_space(3))) void*)l,
        16, 0, 0);
}

// ---------------- x fp32 -> bf16 ----------------
__global__ __launch_bounds__(256) void convert_x_kernel(const float* __restrict__ x,
                                                        unsigned short* __restrict__ xb,
                                                        int n4) {
    int i = blockIdx.x * 256 + threadIdx.x;
    if (i >= n4) return;
    float4 v = ((const float4*)x)[i];
    u16x4 o;
    o.x = f32_to_bf16(v.x);
    o.y = f32_to_bf16(v.y);
    o.z = f32_to_bf16(v.z);
    o.w = f32_to_bf16(v.w);
    *(u16x4*)&xb[(size_t)i * 4] = o;
}

// ---------------- W = dequant(q,scales) + lora_up@lora_down, stored bf16 [OUT][IN] ----------------
__global__ __launch_bounds__(256) void build_w_kernel(const int* __restrict__ q,
                                                      const float* __restrict__ scales,
                                                      const float* __restrict__ up,
                                                      const float* __restrict__ down,
                                                      unsigned short* __restrict__ W) {
    const int o = blockIdx.x;     // output row, 0..4095
    const int t = threadIdx.x;    // 0..255
    __shared__ float u[RANK];
    if (t < RANK) u[t] = up[o * RANK + t];
    __syncthreads();

    const int* qrow = q + (size_t)o * K_TOT;
    const float* srow = scales + (size_t)o * (K_TOT / 32);
    float acc[16];
#pragma unroll
    for (int i = 0; i < 16; i++) {
        int kk = t + 256 * i;
        acc[i] = ((float)qrow[kk] - 128.0f) * srow[kk >> 5];
    }
#pragma unroll
    for (int r = 0; r < RANK; r++) {
        float ur = u[r];
        const float* drow = down + (size_t)r * K_TOT;
#pragma unroll
        for (int i = 0; i < 16; i++) acc[i] += ur * drow[t + 256 * i];
    }
    unsigned short* wrow = W + (size_t)o * K_TOT;
#pragma unroll
    for (int i = 0; i < 16; i++) wrow[t + 256 * i] = f32_to_bf16(acc[i]);
}

// ---------------- C[m][n] = sum_k A[m][k]*B[n][k] + bias[n]  (both bf16 K-major) ----------------
__global__ __launch_bounds__(256) void gemm_bt_kernel(const unsigned short* __restrict__ A,
                                                      const unsigned short* __restrict__ B,
                                                      const float* __restrict__ bias,
                                                      float* __restrict__ C) {
    __shared__ unsigned short As[BM * BK];   // 8 KB, K-major, unpadded (global_load_lds layout)
    __shared__ unsigned short Bs[BN * BK];   // 8 KB

    const int tid  = threadIdx.x;
    const int wave = tid >> 6;       // 0..3
    const int lane = tid & 63;
    const int wm = wave >> 1;        // 0..1 : 64-row half
    const int wn = wave & 1;         // 0..1 : 64-col half

    const int tile_m = (int)blockIdx.y * BM;
    const int tile_n = (int)blockIdx.x * BN;

    // staging: lane covers row r0 + lane/4, 8 elems at k-offset (lane%4)*8
    const int lrow = lane >> 2;
    const int lcol = (lane & 3) * 8;

    const int quad = lane >> 4;      // 0..3
    const int l16  = lane & 15;

    f32x4 acc[4][4];
#pragma unroll
    for (int i = 0; i < 4; i++)
#pragma unroll
        for (int j = 0; j < 4; j++) {
            f32x4 z = {0.f, 0.f, 0.f, 0.f};
            acc[i][j] = z;
        }

    for (int k0 = 0; k0 < K_TOT; k0 += BK) {
#pragma unroll
        for (int j = 0; j < 2; j++) {
            const int r0 = (j * 4 + wave) * 16;   // 16 rows / wave-instruction
            gload_lds16(A + (size_t)(tile_m + r0 + lrow) * K_TOT + (k0 + lcol), &As[r0 * BK]);
            gload_lds16(B + (size_t)(tile_n + r0 + lrow) * K_TOT + (k0 + lcol), &Bs[r0 * BK]);
        }
        __syncthreads();

        bf16x8 af[4], bfr[4];
#pragma unroll
        for (int mi = 0; mi < 4; mi++)
            af[mi] = *(const bf16x8*)&As[(wm * 64 + mi * 16 + l16) * BK + quad * 8];
#pragma unroll
        for (int ni = 0; ni < 4; ni++)
            bfr[ni] = *(const bf16x8*)&Bs[(wn * 64 + ni * 16 + l16) * BK + quad * 8];

#pragma unroll
        for (int mi = 0; mi < 4; mi++)
#pragma unroll
            for (int ni = 0; ni < 4; ni++)
                acc[mi][ni] = __builtin_amdgcn_mfma_f32_16x16x32_bf16(af[mi], bfr[ni], acc[mi][ni], 0, 0, 0);
        __syncthreads();
    }

    // epilogue: D row=(quad*4+r), col=l16 within each 16x16 tile
#pragma unroll
    for (int ni = 0; ni < 4; ni++) {
        const int col = tile_n + wn * 64 + ni * 16 + l16;
        const float bv = bias[col];
#pragma unroll
        for (int mi = 0; mi < 4; mi++) {
#pragma unroll
            for (int r = 0; r < 4; r++) {
                const int row = tile_m + wm * 64 + mi * 16 + quad * 4 + r;
                C[(size_t)row * N_TOT + col] = acc[mi][ni][r] + bv;
            }
        }
    }
}

extern "C" void kernel_launch(void* const* d_in, const int* in_sizes, int n_in,
                              void* d_out, int out_size, void* d_ws, size_t ws_size,
                              hipStream_t stream) {
    const float* x      = (const float*)d_in[0];
    const int*   q      = (const int*)d_in[1];
    const float* scales = (const float*)d_in[2];
    const float* up     = (const float*)d_in[3];
    const float* down   = (const float*)d_in[4];
    const float* bias   = (const float*)d_in[5];
    float* out = (float*)d_out;

    unsigned short* xb = (unsigned short*)d_ws;                 // 8192*4096 bf16 = 64 MB
    unsigned short* wb = xb + (size_t)M_TOT * K_TOT;            // 4096*4096 bf16 = 32 MB

    const int n4 = M_TOT * K_TOT / 4;
    convert_x_kernel<<<n4 / 256, 256, 0, stream>>>(x, xb, n4);
    build_w_kernel<<<N_TOT, 256, 0, stream>>>(q, scales, up, down, wb);
    gemm_bt_kernel<<<dim3(N_TOT / BN, M_TOT / BM), 256, 0, stream>>>(xb, wb, bias, out);
}

// Round 2
// 587.688 us; speedup vs baseline: 1.0586x; 1.0586x over previous
//
#include <hip/hip_runtime.h>
#include <cstdint>
#include <cstddef>

#define M_TOT 8192
#define N_TOT 4096
#define K_TOT 4096
#define RANK  16
#define BM 128
#define BN 128
#define BK 32

typedef float f32x4 __attribute__((ext_vector_type(4)));
typedef __bf16 bf16x8 __attribute__((ext_vector_type(8)));
typedef unsigned short u16x8 __attribute__((ext_vector_type(8)));

__device__ __forceinline__ unsigned short f32_to_bf16(float f) {
    union { float f; uint32_t u; } v; v.f = f;
    uint32_t r = v.u + (0x7fffu + ((v.u >> 16) & 1u));
    return (unsigned short)(r >> 16);
}

// width-16 async global->LDS. dst is wave-uniform base; HW writes lane i at base + i*16B.
__device__ __forceinline__ void gload_lds16(const void* g, void* l) {
    __builtin_amdgcn_global_load_lds(
        (const __attribute__((address_space(1))) void*)g,
        (__attribute__((address_space(3))) void*)l,
        16, 0, 0);
}

// ---------------- x fp32 -> bf16, 8 elems/thread, 16B stores ----------------
__global__ __launch_bounds__(256) void convert_x_kernel(const float* __restrict__ x,
                                                        unsigned short* __restrict__ xb,
                                                        int n8) {
    int i = blockIdx.x * 256 + threadIdx.x;
    if (i >= n8) return;
    float4 a = ((const float4*)x)[2 * (size_t)i];
    float4 b = ((const float4*)x)[2 * (size_t)i + 1];
    u16x8 o;
    o[0] = f32_to_bf16(a.x); o[1] = f32_to_bf16(a.y);
    o[2] = f32_to_bf16(a.z); o[3] = f32_to_bf16(a.w);
    o[4] = f32_to_bf16(b.x); o[5] = f32_to_bf16(b.y);
    o[6] = f32_to_bf16(b.z); o[7] = f32_to_bf16(b.w);
    *(u16x8*)&xb[(size_t)i * 8] = o;
}

// ---- W = dequant(q,scales) + up@down, bf16 [OUT][IN]. 4 rows/block: each
// `down` float4 load is reused across 4 output rows (L2 traffic /4). ----
__global__ __launch_bounds__(256) void build_w_kernel(const int* __restrict__ q,
                                                      const float* __restrict__ scales,
                                                      const float* __restrict__ up,
                                                      const float* __restrict__ down,
                                                      unsigned short* __restrict__ W) {
    const int o0 = blockIdx.x * 4;
    const int t = threadIdx.x;
    __shared__ float u[4][RANK];
    if (t < 64) u[t >> 4][t & 15] = up[(o0 + (t >> 4)) * RANK + (t & 15)];
    __syncthreads();

#pragma unroll
    for (int cc = 0; cc < 2; cc++) {
        const int c = t + 256 * cc;        // 8-elem chunk index, 0..511
        const int k0 = c * 8;
        float acc[4][8];
#pragma unroll
        for (int row = 0; row < 4; row++) {
            const int o = o0 + row;
            int4 qa = *(const int4*)&q[(size_t)o * K_TOT + k0];
            int4 qb = *(const int4*)&q[(size_t)o * K_TOT + k0 + 4];
            const float s = scales[o * (K_TOT / 32) + (k0 >> 5)];
            acc[row][0] = (float)(qa.x - 128) * s;
            acc[row][1] = (float)(qa.y - 128) * s;
            acc[row][2] = (float)(qa.z - 128) * s;
            acc[row][3] = (float)(qa.w - 128) * s;
            acc[row][4] = (float)(qb.x - 128) * s;
            acc[row][5] = (float)(qb.y - 128) * s;
            acc[row][6] = (float)(qb.z - 128) * s;
            acc[row][7] = (float)(qb.w - 128) * s;
        }
#pragma unroll
        for (int r = 0; r < RANK; r++) {
            float4 da = *(const float4*)&down[r * K_TOT + k0];
            float4 db = *(const float4*)&down[r * K_TOT + k0 + 4];
#pragma unroll
            for (int row = 0; row < 4; row++) {
                const float ur = u[row][r];
                acc[row][0] += ur * da.x; acc[row][1] += ur * da.y;
                acc[row][2] += ur * da.z; acc[row][3] += ur * da.w;
                acc[row][4] += ur * db.x; acc[row][5] += ur * db.y;
                acc[row][6] += ur * db.z; acc[row][7] += ur * db.w;
            }
        }
#pragma unroll
        for (int row = 0; row < 4; row++) {
            u16x8 o8;
#pragma unroll
            for (int j = 0; j < 8; j++) o8[j] = f32_to_bf16(acc[row][j]);
            *(u16x8*)&W[(size_t)(o0 + row) * K_TOT + k0] = o8;
        }
    }
}

// ---------------- C[m][n] = sum_k A[m][k]*B[n][k] + bias[n]  (bf16 K-major) ----------------
// LDS layout XOR-swizzled: 16B k-slot g of row r holds global k-group g ^ ((r>>1)&3).
// Relabeling applied at staging-fetch and fragment-read; makes consecutive 8 lanes of a
// ds_read_b128 tile all 8 bank groups (was 4-way colliding).
__global__ __launch_bounds__(256) void gemm_bt_kernel(const unsigned short* __restrict__ A,
                                                      const unsigned short* __restrict__ B,
                                                      const float* __restrict__ bias,
                                                      float* __restrict__ C) {
    __shared__ unsigned short As[BM * BK];   // 8 KB, K-major, unpadded (global_load_lds layout)
    __shared__ unsigned short Bs[BN * BK];   // 8 KB

    const int tid  = threadIdx.x;
    const int wave = tid >> 6;       // 0..3
    const int lane = tid & 63;
    const int wm = wave >> 1;        // 0..1 : 64-row half
    const int wn = wave & 1;         // 0..1 : 64-col half

    const int tile_m = (int)blockIdx.y * BM;
    const int tile_n = (int)blockIdx.x * BN;

    // staging: lane covers row r0 + lane/4; fetches swizzled k-group ((lane&3) ^ ((lrow>>1)&3))
    const int lrow = lane >> 2;
    const int lcol = ((lane & 3) ^ ((lrow >> 1) & 3)) * 8;

    const int quad = lane >> 4;      // 0..3
    const int l16  = lane & 15;
    const int swz  = (l16 >> 1) & 3; // row-dependent slot swizzle (row%16 == l16 here)

    f32x4 acc[4][4];
#pragma unroll
    for (int i = 0; i < 4; i++)
#pragma unroll
        for (int j = 0; j < 4; j++) {
            f32x4 z = {0.f, 0.f, 0.f, 0.f};
            acc[i][j] = z;
        }

    for (int k0 = 0; k0 < K_TOT; k0 += BK) {
#pragma unroll
        for (int j = 0; j < 2; j++) {
            const int r0 = (j * 4 + wave) * 16;   // 16 rows / wave-instruction
            gload_lds16(A + (size_t)(tile_m + r0 + lrow) * K_TOT + (k0 + lcol), &As[r0 * BK]);
            gload_lds16(B + (size_t)(tile_n + r0 + lrow) * K_TOT + (k0 + lcol), &Bs[r0 * BK]);
        }
        __syncthreads();

        const int slot = (quad ^ swz) * 8;
        bf16x8 af[4], bfr[4];
#pragma unroll
        for (int mi = 0; mi < 4; mi++)
            af[mi] = *(const bf16x8*)&As[(wm * 64 + mi * 16 + l16) * BK + slot];
#pragma unroll
        for (int ni = 0; ni < 4; ni++)
            bfr[ni] = *(const bf16x8*)&Bs[(wn * 64 + ni * 16 + l16) * BK + slot];

#pragma unroll
        for (int mi = 0; mi < 4; mi++)
#pragma unroll
            for (int ni = 0; ni < 4; ni++)
                acc[mi][ni] = __builtin_amdgcn_mfma_f32_16x16x32_bf16(af[mi], bfr[ni], acc[mi][ni], 0, 0, 0);
        __syncthreads();
    }

    // epilogue: D row=(quad*4+r), col=l16 within each 16x16 tile
#pragma unroll
    for (int ni = 0; ni < 4; ni++) {
        const int col = tile_n + wn * 64 + ni * 16 + l16;
        const float bv = bias[col];
#pragma unroll
        for (int mi = 0; mi < 4; mi++) {
#pragma unroll
            for (int r = 0; r < 4; r++) {
                const int row = tile_m + wm * 64 + mi * 16 + quad * 4 + r;
                C[(size_t)row * N_TOT + col] = acc[mi][ni][r] + bv;
            }
        }
    }
}

extern "C" void kernel_launch(void* const* d_in, const int* in_sizes, int n_in,
                              void* d_out, int out_size, void* d_ws, size_t ws_size,
                              hipStream_t stream) {
    const float* x      = (const float*)d_in[0];
    const int*   q      = (const int*)d_in[1];
    const float* scales = (const float*)d_in[2];
    const float* up     = (const float*)d_in[3];
    const float* down   = (const float*)d_in[4];
    const float* bias   = (const float*)d_in[5];
    float* out = (float*)d_out;

    unsigned short* xb = (unsigned short*)d_ws;                 // 8192*4096 bf16 = 64 MB
    unsigned short* wb = xb + (size_t)M_TOT * K_TOT;            // 4096*4096 bf16 = 32 MB

    const int n8 = M_TOT * K_TOT / 8;
    convert_x_kernel<<<n8 / 256, 256, 0, stream>>>(x, xb, n8);
    build_w_kernel<<<N_TOT / 4, 256, 0, stream>>>(q, scales, up, down, wb);
    gemm_bt_kernel<<<dim3(N_TOT / BN, M_TOT / BM), 256, 0, stream>>>(xb, wb, bias, out);
}